// Round 6
// baseline (145.451 us; speedup 1.0000x reference)
//
#include <hip/hip_runtime.h>
#include <hip/hip_bf16.h>

#define IN_DIM 512
#define OUT_DIM 512

typedef unsigned short u16;
typedef __attribute__((ext_vector_type(4))) float f32x4;
typedef __attribute__((ext_vector_type(8))) __bf16 bf16x8;

// Direct global->LDS DMA, 16B per lane. LDS dest is wave-uniform base + lane*16.
#define GLD16(gp, lp) __builtin_amdgcn_global_load_lds(                       \
    (const __attribute__((address_space(1))) void*)(gp),                      \
    (__attribute__((address_space(3))) void*)(lp), 16, 0, 0)

#define VMCNT(n) asm volatile("s_waitcnt vmcnt(" #n ")" ::: "memory")
#define SB0()    __builtin_amdgcn_sched_barrier(0)

__device__ __forceinline__ float softplus_f(float r) {
    return (r > 15.0f) ? r : log1pf(expf(r));
}

// ---------------------------------------------------------------------------
// Kernel 1: fold w = w_mu + softplus(w_rho)*w_eps -> bf16 [OUT][IN] (K-major),
//           b = b_mu + softplus(b_rho)*b_eps -> f32 [OUT], into workspace.
// ---------------------------------------------------------------------------
__global__ void prep_kernel(const float* __restrict__ wmu, const float* __restrict__ wrho,
                            const float* __restrict__ weps, const float* __restrict__ bmu,
                            const float* __restrict__ brho, const float* __restrict__ beps,
                            u16* __restrict__ wbf, float* __restrict__ bias) {
    int gid = blockIdx.x * 256 + threadIdx.x;
    int i4 = gid * 4;
    const float4 mu  = *(const float4*)(wmu + i4);
    const float4 rho = *(const float4*)(wrho + i4);
    const float4 ep  = *(const float4*)(weps + i4);
    union { __bf16 h[4]; uint2 u; } pk;
    pk.h[0] = (__bf16)(mu.x + softplus_f(rho.x) * ep.x);
    pk.h[1] = (__bf16)(mu.y + softplus_f(rho.y) * ep.y);
    pk.h[2] = (__bf16)(mu.z + softplus_f(rho.z) * ep.z);
    pk.h[3] = (__bf16)(mu.w + softplus_f(rho.w) * ep.w);
    *(uint2*)(wbf + i4) = pk.u;
    if (gid < OUT_DIM) {
        bias[gid] = bmu[gid] + softplus_f(brho[gid]) * beps[gid];
    }
}

// ---------------------------------------------------------------------------
// Kernel 2: y = x @ w^T + b, fused dropout.
// 3-buffer A-LDS pipeline, counted vmcnt (never 0 in main loop):
//   iter t: load wf(t+1) from L2 | stage(t+2) DMA | compute(t) | vmcnt(8);
//           s_barrier; sched_barrier(0)
// In-order vmcnt: wf(t+1) [>=4] + stage(t+2) [4] are younger than stage(t+1),
// so vmcnt(8) retires exactly stage(t+1) -> one full iteration of HBM cover.
// B (folded bf16 w, 512 KB) is L2-resident: fragments read direct, no LDS.
// A staged f32 via gload_lds, rule-21 swizzle (source-permuted, read-permuted).
// Grid 2048 (512 M x 4 N), 256 thr = 4 waves (2x2). Block 128x128, BK=32.
// ---------------------------------------------------------------------------
__global__ __launch_bounds__(256, 3) void bayes_gemm_kernel(
    const float* __restrict__ x, const float* __restrict__ du,
    const u16* __restrict__ wbf, const float* __restrict__ bias,
    float* __restrict__ out)
{
    __shared__ float lA[3][128 * 32];   // 3 x 16 KB

    const int raw   = blockIdx.x;
    const int lid   = (raw & 7) * 256 + (raw >> 3);   // 2048 % 8 == 0 -> bijective
    const int mband = lid >> 2;      // 0..511
    const int nband = lid & 3;       // 0..3

    const int tid  = threadIdx.x;
    const int lane = tid & 63;
    const int wv   = tid >> 6;
    const int wm   = wv >> 1;        // 0..1
    const int wn   = wv & 1;         // 0..1
    const int l15  = lane & 15;
    const int lk   = lane >> 4;      // 0..3

    const int row0 = mband * 128;
    const int colb = nband * 128;

    // A staging: lane l -> LDS row i*32 + wv*8 + (l>>3), chunk p=(l&7);
    // stored(row,p) holds global chunk c = p ^ (row&7) -> source col swizzled.
    const int arow  = wv * 8 + (lane >> 3);
    const int acswz = ((lane & 7) ^ (lane >> 3)) * 4;
    const float* gA = x + (size_t)(row0 + arow) * IN_DIM + acswz;

    // B fragment pointers (direct from L2-resident wbf)
    const u16* pw0 = wbf + (size_t)(colb + wn * 64 +  0 + l15) * IN_DIM + lk * 8;
    const u16* pw1 = wbf + (size_t)(colb + wn * 64 + 16 + l15) * IN_DIM + lk * 8;
    const u16* pw2 = wbf + (size_t)(colb + wn * 64 + 32 + l15) * IN_DIM + lk * 8;
    const u16* pw3 = wbf + (size_t)(colb + wn * 64 + 48 + l15) * IN_DIM + lk * 8;

    f32x4 acc[4][4] = {};   // [m][n]
    bf16x8 wfc[4], wfn[4];

    auto stage = [&](int t, int buf) {
#pragma unroll
        for (int i = 0; i < 4; ++i)
            GLD16(gA + (size_t)i * 32 * IN_DIM + t * 32,
                  &lA[buf][i * 1024 + wv * 256]);
    };
    auto load_wf = [&](bf16x8* dst, int t) {
        dst[0] = *(const bf16x8*)(pw0 + t * 32);
        dst[1] = *(const bf16x8*)(pw1 + t * 32);
        dst[2] = *(const bf16x8*)(pw2 + t * 32);
        dst[3] = *(const bf16x8*)(pw3 + t * 32);
    };

    // ---- prologue: stage(0), stage(1) in flight; wf(0) loaded.
    stage(0, 0);
    stage(1, 1);
    load_wf(wfc, 0);
    VMCNT(4);                          // stage(0) done regardless of wf placement
    __builtin_amdgcn_s_barrier();
    SB0();

#pragma unroll
    for (int t = 0; t < 16; ++t) {
        if (t + 1 < 16) load_wf(wfn, t + 1);          // L2 loads, used next iter
        if (t + 2 < 16) stage(t + 2, (t + 2) % 3);    // async DMA, 2-deep

        // ---- compute tile t from lA[t%3] with wfc (= wf(t))
#pragma unroll
        for (int m = 0; m < 4; ++m) {
            int r  = wm * 64 + m * 16 + l15;
            int p0 = (2 * lk)     ^ (l15 & 7);
            int p1 = (2 * lk + 1) ^ (l15 & 7);
            float4 a0 = *(const float4*)&lA[t % 3][r * 32 + p0 * 4];
            float4 a1 = *(const float4*)&lA[t % 3][r * 32 + p1 * 4];
            bf16x8 xf;
            xf[0] = (__bf16)a0.x; xf[1] = (__bf16)a0.y;
            xf[2] = (__bf16)a0.z; xf[3] = (__bf16)a0.w;
            xf[4] = (__bf16)a1.x; xf[5] = (__bf16)a1.y;
            xf[6] = (__bf16)a1.z; xf[7] = (__bf16)a1.w;
#pragma unroll
            for (int n = 0; n < 4; ++n)
                acc[m][n] = __builtin_amdgcn_mfma_f32_16x16x32_bf16(
                    wfc[n], xf, acc[m][n], 0, 0, 0);
        }

        // ---- counted drain: retire exactly stage(t+1); keep the rest in flight
        if (t < 14)       { VMCNT(8); }
        else if (t == 14) { VMCNT(4); }
        if (t < 15) {
            __builtin_amdgcn_s_barrier();
            SB0();
        }
#pragma unroll
        for (int n = 0; n < 4; ++n) wfc[n] = wfn[n];
    }

    // ---- epilogue: bias + inverted dropout, dwordx4 throughout
#pragma unroll
    for (int m = 0; m < 4; ++m) {
#pragma unroll
        for (int n = 0; n < 4; ++n) {
            const int colB = colb + wn * 64 + n * 16 + lk * 4;
            const float4 b4 = *(const float4*)(bias + colB);
            size_t off = (size_t)(row0 + wm * 64 + m * 16 + l15) * OUT_DIM + colB;
            const float4 u4 = *(const float4*)(du + off);
            float4 o;
            o.x = (acc[m][n][0] + b4.x) * ((u4.x >= 0.2f) ? 1.25f : 0.0f);
            o.y = (acc[m][n][1] + b4.y) * ((u4.y >= 0.2f) ? 1.25f : 0.0f);
            o.z = (acc[m][n][2] + b4.z) * ((u4.z >= 0.2f) ? 1.25f : 0.0f);
            o.w = (acc[m][n][3] + b4.w) * ((u4.w >= 0.2f) ? 1.25f : 0.0f);
            *(float4*)(out + off) = o;
        }
    }
}

extern "C" void kernel_launch(void* const* d_in, const int* in_sizes, int n_in,
                              void* d_out, int out_size, void* d_ws, size_t ws_size,
                              hipStream_t stream) {
    const float* x    = (const float*)d_in[0];
    const float* wmu  = (const float*)d_in[1];
    const float* wrho = (const float*)d_in[2];
    const float* bmu  = (const float*)d_in[3];
    const float* brho = (const float*)d_in[4];
    const float* weps = (const float*)d_in[5];
    const float* beps = (const float*)d_in[6];
    const float* du   = (const float*)d_in[7];
    float* out = (float*)d_out;

    u16*   wbf  = (u16*)d_ws;
    float* bias = (float*)((char*)d_ws + OUT_DIM * IN_DIM * sizeof(u16));

    prep_kernel<<<256, 256, 0, stream>>>(wmu, wrho, weps, bmu, brho, beps, wbf, bias);
    bayes_gemm_kernel<<<2048, 256, 0, stream>>>(x, du, wbf, bias, out);
}